// Round 1
// baseline (479.693 us; speedup 1.0000x reference)
//
#include <hip/hip_runtime.h>

#define NN 100000
#define NE 1600000
#define ETOT (NE + NN)          // 1,700,000 CSR entries
#define FIN 128
#define FHID 128
#define FOUT 16

#define SCAN_BLK 512
#define SCAN_NB ((NN + SCAN_BLK - 1) / SCAN_BLK)   // 196

// ---------------- graph build ----------------

__global__ void k_init_deg(int* deg) {
    int i = blockIdx.x * blockDim.x + threadIdx.x;
    if (i < NN) deg[i] = 1;                       // self loop
}

__global__ void k_hist(const int* __restrict__ dst, int* deg) {
    int e = blockIdx.x * blockDim.x + threadIdx.x;
    if (e < NE) atomicAdd(&deg[dst[e]], 1);
}

__global__ void k_dinv(const int* __restrict__ deg, float* __restrict__ dinv) {
    int i = blockIdx.x * blockDim.x + threadIdx.x;
    if (i < NN) dinv[i] = rsqrtf((float)deg[i]);  // deg >= 1 always
}

__global__ void k_scan_sums(const int* __restrict__ deg, int* __restrict__ bsums) {
    __shared__ int s[SCAN_BLK];
    int t = threadIdx.x;
    int i = blockIdx.x * SCAN_BLK + t;
    s[t] = (i < NN) ? deg[i] : 0;
    __syncthreads();
    for (int off = SCAN_BLK / 2; off > 0; off >>= 1) {
        if (t < off) s[t] += s[t + off];
        __syncthreads();
    }
    if (t == 0) bsums[blockIdx.x] = s[0];
}

__global__ void k_scan_bsums(int* bsums, int* rowptr_last) {
    if (threadIdx.x == 0 && blockIdx.x == 0) {
        int run = 0;
        for (int i = 0; i < SCAN_NB; ++i) { int v = bsums[i]; bsums[i] = run; run += v; }
        *rowptr_last = run;                       // rowptr[NN] == ETOT
    }
}

__global__ void k_scan_final(const int* __restrict__ deg, const int* __restrict__ bsums,
                             int* __restrict__ rowptr, int* __restrict__ cursor) {
    __shared__ int s[SCAN_BLK];
    int t = threadIdx.x;
    int i = blockIdx.x * SCAN_BLK + t;
    int v = (i < NN) ? deg[i] : 0;
    s[t] = v;
    __syncthreads();
    for (int off = 1; off < SCAN_BLK; off <<= 1) {
        int xv = (t >= off) ? s[t - off] : 0;
        __syncthreads();
        s[t] += xv;
        __syncthreads();
    }
    if (i < NN) {
        int excl = bsums[blockIdx.x] + s[t] - v;  // exclusive scan
        rowptr[i] = excl;
        cursor[i] = excl;
    }
}

__global__ void k_fill(const int* __restrict__ ei, int* cursor, int* __restrict__ col) {
    int idx = blockIdx.x * blockDim.x + threadIdx.x;
    if (idx >= ETOT) return;
    int s, d;
    if (idx < NE) { s = ei[idx]; d = ei[NE + idx]; }
    else          { s = d = idx - NE; }           // self loop
    int pos = atomicAdd(&cursor[d], 1);
    col[pos] = s;
}

// ---------------- GEMM1: h = x @ W1  (100000x128 @ 128x128, fp32) ----------------
// block 256 = 16x16 threads, tile 64Mx64N, K chunked by 32, 4x4 per thread.

__global__ __launch_bounds__(256) void k_gemm1(const float* __restrict__ x,
                                               const float* __restrict__ W,
                                               float* __restrict__ h) {
    __shared__ float xs[64][33];
    __shared__ float ws[32][64];
    int tid = threadIdx.x;
    int tx = tid & 15, ty = tid >> 4;
    int m0 = blockIdx.x * 64;
    int n0 = blockIdx.y * 64;
    float acc[4][4] = {};
    for (int k0 = 0; k0 < FIN; k0 += 32) {
        #pragma unroll
        for (int i = 0; i < 8; ++i) {             // x tile 64x32
            int idx = tid + i * 256;
            int r = idx >> 5, kk = idx & 31;
            int row = m0 + r;
            xs[r][kk] = (row < NN) ? x[row * FIN + k0 + kk] : 0.f;
        }
        #pragma unroll
        for (int i = 0; i < 8; ++i) {             // W tile 32x64
            int idx = tid + i * 256;
            int kk = idx >> 6, c = idx & 63;
            ws[kk][c] = W[(k0 + kk) * FHID + n0 + c];
        }
        __syncthreads();
        #pragma unroll
        for (int kk = 0; kk < 32; ++kk) {
            float4 b4 = *(const float4*)(&ws[kk][tx * 4]);
            float bb[4] = {b4.x, b4.y, b4.z, b4.w};
            float aa[4];
            #pragma unroll
            for (int r = 0; r < 4; ++r) aa[r] = xs[ty * 4 + r][kk];
            #pragma unroll
            for (int r = 0; r < 4; ++r)
                #pragma unroll
                for (int c2 = 0; c2 < 4; ++c2)
                    acc[r][c2] += aa[r] * bb[c2];
        }
        __syncthreads();
    }
    #pragma unroll
    for (int r = 0; r < 4; ++r) {
        int row = m0 + ty * 4 + r;
        if (row < NN) {
            float4 v = make_float4(acc[r][0], acc[r][1], acc[r][2], acc[r][3]);
            *(float4*)&h[row * FHID + n0 + tx * 4] = v;
        }
    }
}

// ---------------- Agg1 + bias + ReLU: out1 = relu(dinv[i]*sum(dinv[s]*h[s]) + b1) ----
// 32 threads per node (float4 each), block 256 = 8 nodes.

__global__ __launch_bounds__(256) void k_agg1(const float* __restrict__ h,
                                              const int* __restrict__ rowptr,
                                              const int* __restrict__ col,
                                              const float* __restrict__ dinv,
                                              const float* __restrict__ b1,
                                              float* __restrict__ out1) {
    int tid = threadIdx.x;
    int node = blockIdx.x * 8 + (tid >> 5);       // grid 12500 -> node < 100000 always
    int fi = (tid & 31) * 4;
    int beg = rowptr[node];
    int end = rowptr[node + 1];
    float ax = 0.f, ay = 0.f, az = 0.f, aw = 0.f;
    for (int e = beg; e < end; ++e) {
        int s = col[e];
        float ds = dinv[s];
        float4 hv = *(const float4*)&h[s * FHID + fi];
        ax += hv.x * ds; ay += hv.y * ds; az += hv.z * ds; aw += hv.w * ds;
    }
    float di = dinv[node];
    float4 bv = *(const float4*)&b1[fi];
    float4 o;
    o.x = fmaxf(ax * di + bv.x, 0.f);
    o.y = fmaxf(ay * di + bv.y, 0.f);
    o.z = fmaxf(az * di + bv.z, 0.f);
    o.w = fmaxf(aw * di + bv.w, 0.f);
    *(float4*)&out1[node * FHID + fi] = o;
}

// ---------------- GEMM2: h2 = out1 @ W2 (100000x128 @ 128x16, fp32) ----------------
// block 256, tile 64 rows; thread (r16,c) computes rows r16+{0,16,32,48}, col c.

__global__ __launch_bounds__(256) void k_gemm2(const float* __restrict__ a,
                                               const float* __restrict__ W,
                                               float* __restrict__ h2) {
    __shared__ float xs[64][129];
    __shared__ float ws[FHID][FOUT];
    int tid = threadIdx.x;
    int c = tid & 15, r16 = tid >> 4;
    int m0 = blockIdx.x * 64;
    #pragma unroll
    for (int i = 0; i < 8; ++i) {                 // W2: 128x16 = 2048
        int idx = tid + i * 256;
        ws[idx >> 4][idx & 15] = W[idx];
    }
    #pragma unroll
    for (int i = 0; i < 32; ++i) {                // a tile 64x128 = 8192
        int idx = tid + i * 256;
        int r = idx >> 7, k = idx & 127;
        int row = m0 + r;
        xs[r][k] = (row < NN) ? a[row * FHID + k] : 0.f;
    }
    __syncthreads();
    float acc[4] = {0.f, 0.f, 0.f, 0.f};
    for (int k = 0; k < FHID; ++k) {
        float w = ws[k][c];
        #pragma unroll
        for (int j = 0; j < 4; ++j)
            acc[j] += xs[r16 + j * 16][k] * w;
    }
    #pragma unroll
    for (int j = 0; j < 4; ++j) {
        int row = m0 + r16 + j * 16;
        if (row < NN) h2[row * FOUT + c] = acc[j];
    }
}

// ---------------- Agg2 + bias: out = dinv[i]*sum(dinv[s]*h2[s]) + b2 ----------------
// 4 threads per node (float4 each), block 256 = 64 nodes.

__global__ __launch_bounds__(256) void k_agg2(const float* __restrict__ h2,
                                              const int* __restrict__ rowptr,
                                              const int* __restrict__ col,
                                              const float* __restrict__ dinv,
                                              const float* __restrict__ b2,
                                              float* __restrict__ out) {
    int tid = threadIdx.x;
    int node = blockIdx.x * 64 + (tid >> 2);
    if (node >= NN) return;
    int fi = (tid & 3) * 4;
    int beg = rowptr[node];
    int end = rowptr[node + 1];
    float ax = 0.f, ay = 0.f, az = 0.f, aw = 0.f;
    for (int e = beg; e < end; ++e) {
        int s = col[e];
        float ds = dinv[s];
        float4 hv = *(const float4*)&h2[s * FOUT + fi];
        ax += hv.x * ds; ay += hv.y * ds; az += hv.z * ds; aw += hv.w * ds;
    }
    float di = dinv[node];
    float4 bv = *(const float4*)&b2[fi];
    float4 o;
    o.x = ax * di + bv.x;
    o.y = ay * di + bv.y;
    o.z = az * di + bv.z;
    o.w = aw * di + bv.w;
    *(float4*)&out[node * FOUT + fi] = o;
}

// ---------------- launch ----------------

extern "C" void kernel_launch(void* const* d_in, const int* in_sizes, int n_in,
                              void* d_out, int out_size, void* d_ws, size_t ws_size,
                              hipStream_t stream) {
    const float* x  = (const float*)d_in[0];
    const int*   ei = (const int*)d_in[1];       // [2][NE]: row0=src, row1=dst
    const float* W1 = (const float*)d_in[2];
    const float* b1 = (const float*)d_in[3];
    const float* W2 = (const float*)d_in[4];
    const float* b2 = (const float*)d_in[5];
    float* out = (float*)d_out;

    char* ws = (char*)d_ws;
    size_t off = 0;
    #define WS_ALLOC(ptr_t, name, bytes) \
        ptr_t name = (ptr_t)(ws + off); off = (off + (size_t)(bytes) + 511) & ~(size_t)511;
    WS_ALLOC(int*,   degI,   (size_t)NN * 4)
    WS_ALLOC(int*,   rowptr, ((size_t)NN + 1) * 4)
    WS_ALLOC(int*,   cursor, (size_t)NN * 4)
    WS_ALLOC(int*,   colv,   (size_t)ETOT * 4)
    WS_ALLOC(float*, dinv,   (size_t)NN * 4)
    WS_ALLOC(int*,   bsums,  (size_t)SCAN_NB * 4)
    WS_ALLOC(float*, h,      (size_t)NN * FHID * 4)
    WS_ALLOC(float*, out1,   (size_t)NN * FHID * 4)
    WS_ALLOC(float*, h2,     (size_t)NN * FOUT * 4)
    #undef WS_ALLOC
    (void)ws_size; (void)in_sizes; (void)n_in; (void)out_size;

    // graph build
    k_init_deg<<<(NN + 255) / 256, 256, 0, stream>>>(degI);
    k_hist<<<(NE + 255) / 256, 256, 0, stream>>>(ei + NE, degI);
    k_dinv<<<(NN + 255) / 256, 256, 0, stream>>>(degI, dinv);
    k_scan_sums<<<SCAN_NB, SCAN_BLK, 0, stream>>>(degI, bsums);
    k_scan_bsums<<<1, 64, 0, stream>>>(bsums, rowptr + NN);
    k_scan_final<<<SCAN_NB, SCAN_BLK, 0, stream>>>(degI, bsums, rowptr, cursor);
    k_fill<<<(ETOT + 255) / 256, 256, 0, stream>>>(ei, cursor, colv);

    // layer 1
    k_gemm1<<<dim3((NN + 63) / 64, 2), 256, 0, stream>>>(x, W1, h);
    k_agg1<<<NN / 8, 256, 0, stream>>>(h, rowptr, colv, dinv, b1, out1);

    // layer 2
    k_gemm2<<<(NN + 63) / 64, 256, 0, stream>>>(out1, W2, h2);
    k_agg2<<<(NN + 63) / 64, 256, 0, stream>>>(h2, rowptr, colv, dinv, b2, out);
}

// Round 2
// 419.241 us; speedup vs baseline: 1.1442x; 1.1442x over previous
//
#include <hip/hip_runtime.h>

#define NN 100000
#define NE 1600000
#define ETOT (NE + NN)          // 1,700,000 CSR entries
#define FIN 128
#define FHID 128
#define FOUT 16

#define SCAN_BLK 512
#define SCAN_NB ((NN + SCAN_BLK - 1) / SCAN_BLK)   // 196

#define NRANGE 8
#define RANGE_W (NN / NRANGE)   // 12500
#define FILL_CHUNKS 256         // blocks per range; grid = 8*256 = 2048

// ---------------- graph build ----------------

__global__ void k_init_deg(int* deg) {
    int i = blockIdx.x * blockDim.x + threadIdx.x;
    if (i < NN) deg[i] = 1;                       // self loop
}

__global__ void k_hist(const int* __restrict__ dst, int* deg) {
    int e = blockIdx.x * blockDim.x + threadIdx.x;
    if (e < NE) atomicAdd(&deg[dst[e]], 1);
}

__global__ void k_dinv(const int* __restrict__ deg, float* __restrict__ dinv) {
    int i = blockIdx.x * blockDim.x + threadIdx.x;
    if (i < NN) dinv[i] = rsqrtf((float)deg[i]);  // deg >= 1 always
}

__global__ void k_scan_sums(const int* __restrict__ deg, int* __restrict__ bsums) {
    __shared__ int s[SCAN_BLK];
    int t = threadIdx.x;
    int i = blockIdx.x * SCAN_BLK + t;
    s[t] = (i < NN) ? deg[i] : 0;
    __syncthreads();
    for (int off = SCAN_BLK / 2; off > 0; off >>= 1) {
        if (t < off) s[t] += s[t + off];
        __syncthreads();
    }
    if (t == 0) bsums[blockIdx.x] = s[0];
}

// parallel exclusive scan of the 196 block sums (single block of 256)
__global__ void k_scan_bsums(int* bsums, int* rowptr_last) {
    __shared__ int s[256];
    int t = threadIdx.x;
    int v = (t < SCAN_NB) ? bsums[t] : 0;
    s[t] = v;
    __syncthreads();
    for (int off = 1; off < 256; off <<= 1) {
        int xv = (t >= off) ? s[t - off] : 0;
        __syncthreads();
        s[t] += xv;
        __syncthreads();
    }
    if (t < SCAN_NB) bsums[t] = s[t] - v;         // exclusive
    if (t == 0) *rowptr_last = s[255];            // total == ETOT
}

__global__ void k_scan_final(const int* __restrict__ deg, const int* __restrict__ bsums,
                             int* __restrict__ rowptr, int* __restrict__ cursor) {
    __shared__ int s[SCAN_BLK];
    int t = threadIdx.x;
    int i = blockIdx.x * SCAN_BLK + t;
    int v = (i < NN) ? deg[i] : 0;
    s[t] = v;
    __syncthreads();
    for (int off = 1; off < SCAN_BLK; off <<= 1) {
        int xv = (t >= off) ? s[t - off] : 0;
        __syncthreads();
        s[t] += xv;
        __syncthreads();
    }
    if (i < NN) {
        int excl = bsums[blockIdx.x] + s[t] - v;  // exclusive scan
        rowptr[i] = excl;
        cursor[i] = excl;
    }
}

// CSR fill, dst-range partitioned so each col cache line is written by one
// XCD only (range = blockIdx.x % 8 ~ XCD id on MI355X). Each range scans all
// edges (dst re-read 8x, sequential ~51MB, cheap) but writes only its own
// 0.85MB col region -> L2-resident, written back to HBM once (was 16x amp).
__global__ __launch_bounds__(256) void k_fill(const int* __restrict__ ei,
                                              int* cursor, int* __restrict__ col) {
    int range = blockIdx.x & (NRANGE - 1);
    int chunk = blockIdx.x >> 3;
    int lo = range * RANGE_W, hi = lo + RANGE_W;
    const int stride = FILL_CHUNKS * 256 * 4;     // 262144
    for (int base = (chunk * 256 + threadIdx.x) * 4; base < NE; base += stride) {
        int4 d4 = *(const int4*)&ei[NE + base];
        int dd[4] = {d4.x, d4.y, d4.z, d4.w};
        #pragma unroll
        for (int j = 0; j < 4; ++j) {
            int d = dd[j];
            if (d >= lo && d < hi) {
                int s = ei[base + j];
                int pos = atomicAdd(&cursor[d], 1);
                col[pos] = s;
            }
        }
    }
    // self loops belonging to this range (kept XCD-local)
    for (int i = lo + chunk * 256 + threadIdx.x; i < hi; i += FILL_CHUNKS * 256) {
        int pos = atomicAdd(&cursor[i], 1);
        col[pos] = i;
    }
}

// ---------------- GEMM1: h = x @ W1  (100000x128 @ 128x128, fp32) ----------------
// block 256 = 16x16 threads, tile 64Mx64N, K chunked by 32, 4x4 per thread.

__global__ __launch_bounds__(256) void k_gemm1(const float* __restrict__ x,
                                               const float* __restrict__ W,
                                               float* __restrict__ h) {
    __shared__ float xs[64][33];
    __shared__ float ws[32][64];
    int tid = threadIdx.x;
    int tx = tid & 15, ty = tid >> 4;
    int m0 = blockIdx.x * 64;
    int n0 = blockIdx.y * 64;
    float acc[4][4] = {};
    for (int k0 = 0; k0 < FIN; k0 += 32) {
        #pragma unroll
        for (int i = 0; i < 8; ++i) {             // x tile 64x32
            int idx = tid + i * 256;
            int r = idx >> 5, kk = idx & 31;
            int row = m0 + r;
            xs[r][kk] = (row < NN) ? x[row * FIN + k0 + kk] : 0.f;
        }
        #pragma unroll
        for (int i = 0; i < 8; ++i) {             // W tile 32x64
            int idx = tid + i * 256;
            int kk = idx >> 6, c = idx & 63;
            ws[kk][c] = W[(k0 + kk) * FHID + n0 + c];
        }
        __syncthreads();
        #pragma unroll
        for (int kk = 0; kk < 32; ++kk) {
            float4 b4 = *(const float4*)(&ws[kk][tx * 4]);
            float bb[4] = {b4.x, b4.y, b4.z, b4.w};
            float aa[4];
            #pragma unroll
            for (int r = 0; r < 4; ++r) aa[r] = xs[ty * 4 + r][kk];
            #pragma unroll
            for (int r = 0; r < 4; ++r)
                #pragma unroll
                for (int c2 = 0; c2 < 4; ++c2)
                    acc[r][c2] += aa[r] * bb[c2];
        }
        __syncthreads();
    }
    #pragma unroll
    for (int r = 0; r < 4; ++r) {
        int row = m0 + ty * 4 + r;
        if (row < NN) {
            float4 v = make_float4(acc[r][0], acc[r][1], acc[r][2], acc[r][3]);
            *(float4*)&h[row * FHID + n0 + tx * 4] = v;
        }
    }
}

// ---------------- Agg1 + bias + ReLU: out1 = relu(dinv[i]*sum(dinv[s]*h[s]) + b1) ----
// 32 threads per node (float4 each), block 256 = 8 nodes.

__global__ __launch_bounds__(256) void k_agg1(const float* __restrict__ h,
                                              const int* __restrict__ rowptr,
                                              const int* __restrict__ col,
                                              const float* __restrict__ dinv,
                                              const float* __restrict__ b1,
                                              float* __restrict__ out1) {
    int tid = threadIdx.x;
    int node = blockIdx.x * 8 + (tid >> 5);       // grid 12500 -> node < 100000 always
    int fi = (tid & 31) * 4;
    int beg = rowptr[node];
    int end = rowptr[node + 1];
    float ax = 0.f, ay = 0.f, az = 0.f, aw = 0.f;
    for (int e = beg; e < end; ++e) {
        int s = col[e];
        float ds = dinv[s];
        float4 hv = *(const float4*)&h[s * FHID + fi];
        ax += hv.x * ds; ay += hv.y * ds; az += hv.z * ds; aw += hv.w * ds;
    }
    float di = dinv[node];
    float4 bv = *(const float4*)&b1[fi];
    float4 o;
    o.x = fmaxf(ax * di + bv.x, 0.f);
    o.y = fmaxf(ay * di + bv.y, 0.f);
    o.z = fmaxf(az * di + bv.z, 0.f);
    o.w = fmaxf(aw * di + bv.w, 0.f);
    *(float4*)&out1[node * FHID + fi] = o;
}

// ---------------- GEMM2: h2 = out1 @ W2 (100000x128 @ 128x16, fp32) ----------------
// block 256, tile 64 rows; thread (r16,c) computes rows r16+{0,16,32,48}, col c.

__global__ __launch_bounds__(256) void k_gemm2(const float* __restrict__ a,
                                               const float* __restrict__ W,
                                               float* __restrict__ h2) {
    __shared__ float xs[64][129];
    __shared__ float ws[FHID][FOUT];
    int tid = threadIdx.x;
    int c = tid & 15, r16 = tid >> 4;
    int m0 = blockIdx.x * 64;
    #pragma unroll
    for (int i = 0; i < 8; ++i) {                 // W2: 128x16 = 2048
        int idx = tid + i * 256;
        ws[idx >> 4][idx & 15] = W[idx];
    }
    #pragma unroll
    for (int i = 0; i < 32; ++i) {                // a tile 64x128 = 8192
        int idx = tid + i * 256;
        int r = idx >> 7, k = idx & 127;
        int row = m0 + r;
        xs[r][k] = (row < NN) ? a[row * FHID + k] : 0.f;
    }
    __syncthreads();
    float acc[4] = {0.f, 0.f, 0.f, 0.f};
    for (int k = 0; k < FHID; ++k) {
        float w = ws[k][c];
        #pragma unroll
        for (int j = 0; j < 4; ++j)
            acc[j] += xs[r16 + j * 16][k] * w;
    }
    #pragma unroll
    for (int j = 0; j < 4; ++j) {
        int row = m0 + r16 + j * 16;
        if (row < NN) h2[row * FOUT + c] = acc[j];
    }
}

// ---------------- Agg2 + bias: out = dinv[i]*sum(dinv[s]*h2[s]) + b2 ----------------
// 4 threads per node (float4 each), block 256 = 64 nodes.

__global__ __launch_bounds__(256) void k_agg2(const float* __restrict__ h2,
                                              const int* __restrict__ rowptr,
                                              const int* __restrict__ col,
                                              const float* __restrict__ dinv,
                                              const float* __restrict__ b2,
                                              float* __restrict__ out) {
    int tid = threadIdx.x;
    int node = blockIdx.x * 64 + (tid >> 2);
    if (node >= NN) return;
    int fi = (tid & 3) * 4;
    int beg = rowptr[node];
    int end = rowptr[node + 1];
    float ax = 0.f, ay = 0.f, az = 0.f, aw = 0.f;
    for (int e = beg; e < end; ++e) {
        int s = col[e];
        float ds = dinv[s];
        float4 hv = *(const float4*)&h2[s * FOUT + fi];
        ax += hv.x * ds; ay += hv.y * ds; az += hv.z * ds; aw += hv.w * ds;
    }
    float di = dinv[node];
    float4 bv = *(const float4*)&b2[fi];
    float4 o;
    o.x = ax * di + bv.x;
    o.y = ay * di + bv.y;
    o.z = az * di + bv.z;
    o.w = aw * di + bv.w;
    *(float4*)&out[node * FOUT + fi] = o;
}

// ---------------- launch ----------------

extern "C" void kernel_launch(void* const* d_in, const int* in_sizes, int n_in,
                              void* d_out, int out_size, void* d_ws, size_t ws_size,
                              hipStream_t stream) {
    const float* x  = (const float*)d_in[0];
    const int*   ei = (const int*)d_in[1];       // [2][NE]: row0=src, row1=dst
    const float* W1 = (const float*)d_in[2];
    const float* b1 = (const float*)d_in[3];
    const float* W2 = (const float*)d_in[4];
    const float* b2 = (const float*)d_in[5];
    float* out = (float*)d_out;

    char* ws = (char*)d_ws;
    size_t off = 0;
    #define WS_ALLOC(ptr_t, name, bytes) \
        ptr_t name = (ptr_t)(ws + off); off = (off + (size_t)(bytes) + 511) & ~(size_t)511;
    WS_ALLOC(int*,   degI,   (size_t)NN * 4)
    WS_ALLOC(int*,   rowptr, ((size_t)NN + 1) * 4)
    WS_ALLOC(int*,   cursor, (size_t)NN * 4)
    WS_ALLOC(int*,   colv,   (size_t)ETOT * 4)
    WS_ALLOC(float*, dinv,   (size_t)NN * 4)
    WS_ALLOC(int*,   bsums,  (size_t)SCAN_NB * 4)
    WS_ALLOC(float*, h,      (size_t)NN * FHID * 4)
    WS_ALLOC(float*, out1,   (size_t)NN * FHID * 4)
    WS_ALLOC(float*, h2,     (size_t)NN * FOUT * 4)
    #undef WS_ALLOC
    (void)ws_size; (void)in_sizes; (void)n_in; (void)out_size;

    // graph build
    k_init_deg<<<(NN + 255) / 256, 256, 0, stream>>>(degI);
    k_hist<<<(NE + 255) / 256, 256, 0, stream>>>(ei + NE, degI);
    k_dinv<<<(NN + 255) / 256, 256, 0, stream>>>(degI, dinv);
    k_scan_sums<<<SCAN_NB, SCAN_BLK, 0, stream>>>(degI, bsums);
    k_scan_bsums<<<1, 256, 0, stream>>>(bsums, rowptr + NN);
    k_scan_final<<<SCAN_NB, SCAN_BLK, 0, stream>>>(degI, bsums, rowptr, cursor);
    k_fill<<<NRANGE * FILL_CHUNKS, 256, 0, stream>>>(ei, cursor, colv);

    // layer 1
    k_gemm1<<<dim3((NN + 63) / 64, 2), 256, 0, stream>>>(x, W1, h);
    k_agg1<<<NN / 8, 256, 0, stream>>>(h, rowptr, colv, dinv, b1, out1);

    // layer 2
    k_gemm2<<<(NN + 63) / 64, 256, 0, stream>>>(out1, W2, h2);
    k_agg2<<<(NN + 63) / 64, 256, 0, stream>>>(h2, rowptr, colv, dinv, b2, out);
}

// Round 3
// 316.443 us; speedup vs baseline: 1.5159x; 1.3249x over previous
//
#include <hip/hip_runtime.h>
#include <hip/hip_fp16.h>

#define NN 100000
#define NE 1600000
#define ETOT (NE + NN)          // 1,700,000 CSR entries
#define FIN 128
#define FHID 128
#define FOUT 16

#define SCAN_BLK 512
#define SCAN_NB ((NN + SCAN_BLK - 1) / SCAN_BLK)   // 196

#define NRANGE 8
#define RANGE_W (NN / NRANGE)   // 12500
#define FILL_CHUNKS 256         // blocks per range; grid = 8*256 = 2048

// ---------------- graph build ----------------

__global__ void k_init_deg(int* deg) {
    int i = blockIdx.x * blockDim.x + threadIdx.x;
    if (i < NN) deg[i] = 1;                       // self loop
}

__global__ void k_hist(const int* __restrict__ dst, int* deg) {
    int e = blockIdx.x * blockDim.x + threadIdx.x;
    if (e < NE) atomicAdd(&deg[dst[e]], 1);
}

__global__ void k_dinv(const int* __restrict__ deg, float* __restrict__ dinv) {
    int i = blockIdx.x * blockDim.x + threadIdx.x;
    if (i < NN) dinv[i] = rsqrtf((float)deg[i]);  // deg >= 1 always
}

__global__ void k_scan_sums(const int* __restrict__ deg, int* __restrict__ bsums) {
    __shared__ int s[SCAN_BLK];
    int t = threadIdx.x;
    int i = blockIdx.x * SCAN_BLK + t;
    s[t] = (i < NN) ? deg[i] : 0;
    __syncthreads();
    for (int off = SCAN_BLK / 2; off > 0; off >>= 1) {
        if (t < off) s[t] += s[t + off];
        __syncthreads();
    }
    if (t == 0) bsums[blockIdx.x] = s[0];
}

// parallel exclusive scan of the 196 block sums (single block of 256)
__global__ void k_scan_bsums(int* bsums, int* rowptr_last) {
    __shared__ int s[256];
    int t = threadIdx.x;
    int v = (t < SCAN_NB) ? bsums[t] : 0;
    s[t] = v;
    __syncthreads();
    for (int off = 1; off < 256; off <<= 1) {
        int xv = (t >= off) ? s[t - off] : 0;
        __syncthreads();
        s[t] += xv;
        __syncthreads();
    }
    if (t < SCAN_NB) bsums[t] = s[t] - v;         // exclusive
    if (t == 0) *rowptr_last = s[255];            // total == ETOT
}

__global__ void k_scan_final(const int* __restrict__ deg, const int* __restrict__ bsums,
                             int* __restrict__ rowptr, int* __restrict__ cursor) {
    __shared__ int s[SCAN_BLK];
    int t = threadIdx.x;
    int i = blockIdx.x * SCAN_BLK + t;
    int v = (i < NN) ? deg[i] : 0;
    s[t] = v;
    __syncthreads();
    for (int off = 1; off < SCAN_BLK; off <<= 1) {
        int xv = (t >= off) ? s[t - off] : 0;
        __syncthreads();
        s[t] += xv;
        __syncthreads();
    }
    if (i < NN) {
        int excl = bsums[blockIdx.x] + s[t] - v;  // exclusive scan
        rowptr[i] = excl;
        cursor[i] = excl;
    }
}

// CSR fill, dst-range partitioned: each col cache line written by one XCD only
// (range = blockIdx.x % 8 ~ XCD id). Cut write amplification 108MB -> ~11MB.
__global__ __launch_bounds__(256) void k_fill(const int* __restrict__ ei,
                                              int* cursor, int* __restrict__ col) {
    int range = blockIdx.x & (NRANGE - 1);
    int chunk = blockIdx.x >> 3;
    int lo = range * RANGE_W, hi = lo + RANGE_W;
    const int stride = FILL_CHUNKS * 256 * 4;     // 262144
    for (int base = (chunk * 256 + threadIdx.x) * 4; base < NE; base += stride) {
        int4 d4 = *(const int4*)&ei[NE + base];
        int dd[4] = {d4.x, d4.y, d4.z, d4.w};
        #pragma unroll
        for (int j = 0; j < 4; ++j) {
            int d = dd[j];
            if (d >= lo && d < hi) {
                int s = ei[base + j];
                int pos = atomicAdd(&cursor[d], 1);
                col[pos] = s;
            }
        }
    }
    for (int i = lo + chunk * 256 + threadIdx.x; i < hi; i += FILL_CHUNKS * 256) {
        int pos = atomicAdd(&cursor[i], 1);
        col[pos] = i;
    }
}

// ---------------- GEMM1: h = x @ W1 -> fp16 [NN][64] half2 ----------------

__global__ __launch_bounds__(256) void k_gemm1(const float* __restrict__ x,
                                               const float* __restrict__ W,
                                               __half2* __restrict__ hf) {
    __shared__ float xs[64][33];
    __shared__ float ws[32][64];
    int tid = threadIdx.x;
    int tx = tid & 15, ty = tid >> 4;
    int m0 = blockIdx.x * 64;
    int n0 = blockIdx.y * 64;
    float acc[4][4] = {};
    for (int k0 = 0; k0 < FIN; k0 += 32) {
        #pragma unroll
        for (int i = 0; i < 8; ++i) {             // x tile 64x32
            int idx = tid + i * 256;
            int r = idx >> 5, kk = idx & 31;
            int row = m0 + r;
            xs[r][kk] = (row < NN) ? x[row * FIN + k0 + kk] : 0.f;
        }
        #pragma unroll
        for (int i = 0; i < 8; ++i) {             // W tile 32x64
            int idx = tid + i * 256;
            int kk = idx >> 6, c = idx & 63;
            ws[kk][c] = W[(k0 + kk) * FHID + n0 + c];
        }
        __syncthreads();
        #pragma unroll
        for (int kk = 0; kk < 32; ++kk) {
            float4 b4 = *(const float4*)(&ws[kk][tx * 4]);
            float bb[4] = {b4.x, b4.y, b4.z, b4.w};
            float aa[4];
            #pragma unroll
            for (int r = 0; r < 4; ++r) aa[r] = xs[ty * 4 + r][kk];
            #pragma unroll
            for (int r = 0; r < 4; ++r)
                #pragma unroll
                for (int c2 = 0; c2 < 4; ++c2)
                    acc[r][c2] += aa[r] * bb[c2];
        }
        __syncthreads();
    }
    #pragma unroll
    for (int r = 0; r < 4; ++r) {
        int row = m0 + ty * 4 + r;
        if (row < NN) {
            __half2 q[2];
            q[0] = __floats2half2_rn(acc[r][0], acc[r][1]);
            q[1] = __floats2half2_rn(acc[r][2], acc[r][3]);
            *reinterpret_cast<int2*>(hf + (size_t)row * 64 + (n0 >> 1) + tx * 2) =
                *reinterpret_cast<int2*>(q);
        }
    }
}

// ---------------- aggregation helpers ----------------

__device__ __forceinline__ void acc_row8(float* acc, int4 raw, float d) {
    const __half2* p = reinterpret_cast<const __half2*>(&raw);
    #pragma unroll
    for (int j = 0; j < 4; ++j) {
        float2 f = __half22float2(p[j]);
        acc[2 * j]     += f.x * d;
        acc[2 * j + 1] += f.y * d;
    }
}

// ---------------- Agg1 + bias + ReLU -> out1 fp16 [NN][64] half2 ----------------
// 16 lanes per node (16B fp16 each), block 256 = 16 nodes. Edge loop unrolled x4
// for memory-level parallelism (4 independent 16B gathers in flight).

__global__ __launch_bounds__(256) void k_agg1(const __half2* __restrict__ hf,
                                              const int* __restrict__ rowptr,
                                              const int* __restrict__ col,
                                              const float* __restrict__ dinv,
                                              const float* __restrict__ b1,
                                              __half2* __restrict__ out1) {
    int tid = threadIdx.x;
    int node = blockIdx.x * 16 + (tid >> 4);      // grid 6250 exact
    int lane = tid & 15;                          // features lane*8 .. lane*8+7
    int beg = rowptr[node];
    int end = rowptr[node + 1];
    float acc[8] = {};
    int e = beg;
    for (; e + 4 <= end; e += 4) {
        int s0 = col[e], s1 = col[e + 1], s2 = col[e + 2], s3 = col[e + 3];
        float d0 = dinv[s0], d1 = dinv[s1], d2 = dinv[s2], d3 = dinv[s3];
        int4 r0 = *reinterpret_cast<const int4*>(hf + (size_t)s0 * 64 + lane * 4);
        int4 r1 = *reinterpret_cast<const int4*>(hf + (size_t)s1 * 64 + lane * 4);
        int4 r2 = *reinterpret_cast<const int4*>(hf + (size_t)s2 * 64 + lane * 4);
        int4 r3 = *reinterpret_cast<const int4*>(hf + (size_t)s3 * 64 + lane * 4);
        acc_row8(acc, r0, d0);
        acc_row8(acc, r1, d1);
        acc_row8(acc, r2, d2);
        acc_row8(acc, r3, d3);
    }
    for (; e < end; ++e) {
        int s = col[e];
        float d = dinv[s];
        int4 r = *reinterpret_cast<const int4*>(hf + (size_t)s * 64 + lane * 4);
        acc_row8(acc, r, d);
    }
    float di = dinv[node];
    float4 bA = *(const float4*)&b1[lane * 8];
    float4 bB = *(const float4*)&b1[lane * 8 + 4];
    float o[8];
    o[0] = fmaxf(acc[0] * di + bA.x, 0.f);
    o[1] = fmaxf(acc[1] * di + bA.y, 0.f);
    o[2] = fmaxf(acc[2] * di + bA.z, 0.f);
    o[3] = fmaxf(acc[3] * di + bA.w, 0.f);
    o[4] = fmaxf(acc[4] * di + bB.x, 0.f);
    o[5] = fmaxf(acc[5] * di + bB.y, 0.f);
    o[6] = fmaxf(acc[6] * di + bB.z, 0.f);
    o[7] = fmaxf(acc[7] * di + bB.w, 0.f);
    __half2 ph[4];
    #pragma unroll
    for (int j = 0; j < 4; ++j) ph[j] = __floats2half2_rn(o[2 * j], o[2 * j + 1]);
    *reinterpret_cast<int4*>(out1 + (size_t)node * 64 + lane * 4) =
        *reinterpret_cast<int4*>(ph);
}

// ---------------- GEMM2: h2 = out1 @ W2 -> fp16 [NN][8] half2 ----------------
// block 256: thread = (cp 0..7 col-pair, r 0..31); computes rows r, r+32.

__global__ __launch_bounds__(256) void k_gemm2(const __half2* __restrict__ a,
                                               const float* __restrict__ W,
                                               __half2* __restrict__ h2) {
    __shared__ __half2 xs[64][68];                // 64 rows x 64 half2 (+4 pad)
    __shared__ float ws[FHID][FOUT];
    int tid = threadIdx.x;
    int m0 = blockIdx.x * 64;
    #pragma unroll
    for (int i = 0; i < 8; ++i) {                 // W2: 128x16
        int idx = tid + i * 256;
        ws[idx >> 4][idx & 15] = W[idx];
    }
    #pragma unroll
    for (int i = 0; i < 4; ++i) {                 // a tile: 64 rows x 16 int4
        int idx = tid + i * 256;
        int r = idx >> 4, q = idx & 15;
        int row = m0 + r;
        int4 v = make_int4(0, 0, 0, 0);
        if (row < NN) v = *reinterpret_cast<const int4*>(a + (size_t)row * 64 + q * 4);
        *reinterpret_cast<int4*>(&xs[r][q * 4]) = v;
    }
    __syncthreads();
    int cp = tid & 7, r = tid >> 3;               // r in 0..31
    float a00 = 0.f, a01 = 0.f, a10 = 0.f, a11 = 0.f;
    #pragma unroll 8
    for (int k2 = 0; k2 < 64; ++k2) {
        float2 f0 = __half22float2(xs[r][k2]);
        float2 f1 = __half22float2(xs[r + 32][k2]);
        float wa0 = ws[2 * k2][2 * cp],     wb0 = ws[2 * k2][2 * cp + 1];
        float wa1 = ws[2 * k2 + 1][2 * cp], wb1 = ws[2 * k2 + 1][2 * cp + 1];
        a00 += f0.x * wa0 + f0.y * wa1;
        a01 += f0.x * wb0 + f0.y * wb1;
        a10 += f1.x * wa0 + f1.y * wa1;
        a11 += f1.x * wb0 + f1.y * wb1;
    }
    int row0 = m0 + r, row1 = m0 + r + 32;
    if (row0 < NN) h2[(size_t)row0 * 8 + cp] = __floats2half2_rn(a00, a01);
    if (row1 < NN) h2[(size_t)row1 * 8 + cp] = __floats2half2_rn(a10, a11);
}

// ---------------- Agg2 + bias -> out fp32 ----------------
// 2 lanes per node (16B fp16 each), block 256 = 128 nodes, unroll x4.

__global__ __launch_bounds__(256) void k_agg2(const __half2* __restrict__ h2,
                                              const int* __restrict__ rowptr,
                                              const int* __restrict__ col,
                                              const float* __restrict__ dinv,
                                              const float* __restrict__ b2,
                                              float* __restrict__ out) {
    int tid = threadIdx.x;
    int node = blockIdx.x * 128 + (tid >> 1);
    if (node >= NN) return;
    int l = tid & 1;                              // features l*8 .. l*8+7
    int beg = rowptr[node];
    int end = rowptr[node + 1];
    float acc[8] = {};
    int e = beg;
    for (; e + 4 <= end; e += 4) {
        int s0 = col[e], s1 = col[e + 1], s2 = col[e + 2], s3 = col[e + 3];
        float d0 = dinv[s0], d1 = dinv[s1], d2 = dinv[s2], d3 = dinv[s3];
        int4 r0 = *reinterpret_cast<const int4*>(h2 + (size_t)s0 * 8 + l * 4);
        int4 r1 = *reinterpret_cast<const int4*>(h2 + (size_t)s1 * 8 + l * 4);
        int4 r2 = *reinterpret_cast<const int4*>(h2 + (size_t)s2 * 8 + l * 4);
        int4 r3 = *reinterpret_cast<const int4*>(h2 + (size_t)s3 * 8 + l * 4);
        acc_row8(acc, r0, d0);
        acc_row8(acc, r1, d1);
        acc_row8(acc, r2, d2);
        acc_row8(acc, r3, d3);
    }
    for (; e < end; ++e) {
        int s = col[e];
        float d = dinv[s];
        int4 r = *reinterpret_cast<const int4*>(h2 + (size_t)s * 8 + l * 4);
        acc_row8(acc, r, d);
    }
    float di = dinv[node];
    float4 bA = *(const float4*)&b2[l * 8];
    float4 bB = *(const float4*)&b2[l * 8 + 4];
    float4 oA, oB;
    oA.x = acc[0] * di + bA.x;  oA.y = acc[1] * di + bA.y;
    oA.z = acc[2] * di + bA.z;  oA.w = acc[3] * di + bA.w;
    oB.x = acc[4] * di + bB.x;  oB.y = acc[5] * di + bB.y;
    oB.z = acc[6] * di + bB.z;  oB.w = acc[7] * di + bB.w;
    *(float4*)&out[(size_t)node * 16 + l * 8] = oA;
    *(float4*)&out[(size_t)node * 16 + l * 8 + 4] = oB;
}

// ---------------- launch ----------------

extern "C" void kernel_launch(void* const* d_in, const int* in_sizes, int n_in,
                              void* d_out, int out_size, void* d_ws, size_t ws_size,
                              hipStream_t stream) {
    const float* x  = (const float*)d_in[0];
    const int*   ei = (const int*)d_in[1];       // [2][NE]: row0=src, row1=dst
    const float* W1 = (const float*)d_in[2];
    const float* b1 = (const float*)d_in[3];
    const float* W2 = (const float*)d_in[4];
    const float* b2 = (const float*)d_in[5];
    float* out = (float*)d_out;

    char* ws = (char*)d_ws;
    size_t off = 0;
    #define WS_ALLOC(ptr_t, name, bytes) \
        ptr_t name = (ptr_t)(ws + off); off = (off + (size_t)(bytes) + 511) & ~(size_t)511;
    WS_ALLOC(int*,      degI,   (size_t)NN * 4)
    WS_ALLOC(int*,      rowptr, ((size_t)NN + 1) * 4)
    WS_ALLOC(int*,      cursor, (size_t)NN * 4)
    WS_ALLOC(int*,      colv,   (size_t)ETOT * 4)
    WS_ALLOC(float*,    dinv,   (size_t)NN * 4)
    WS_ALLOC(int*,      bsums,  (size_t)SCAN_NB * 4)
    WS_ALLOC(__half2*,  hf,     (size_t)NN * FHID * 2)
    WS_ALLOC(__half2*,  out1f,  (size_t)NN * FHID * 2)
    WS_ALLOC(__half2*,  h2f,    (size_t)NN * FOUT * 2)
    #undef WS_ALLOC
    (void)ws_size; (void)in_sizes; (void)n_in; (void)out_size;

    // graph build
    k_init_deg<<<(NN + 255) / 256, 256, 0, stream>>>(degI);
    k_hist<<<(NE + 255) / 256, 256, 0, stream>>>(ei + NE, degI);
    k_dinv<<<(NN + 255) / 256, 256, 0, stream>>>(degI, dinv);
    k_scan_sums<<<SCAN_NB, SCAN_BLK, 0, stream>>>(degI, bsums);
    k_scan_bsums<<<1, 256, 0, stream>>>(bsums, rowptr + NN);
    k_scan_final<<<SCAN_NB, SCAN_BLK, 0, stream>>>(degI, bsums, rowptr, cursor);
    k_fill<<<NRANGE * FILL_CHUNKS, 256, 0, stream>>>(ei, cursor, colv);

    // layer 1
    k_gemm1<<<dim3((NN + 63) / 64, 2), 256, 0, stream>>>(x, W1, hf);
    k_agg1<<<NN / 16, 256, 0, stream>>>(hf, rowptr, colv, dinv, b1, out1f);

    // layer 2
    k_gemm2<<<(NN + 63) / 64, 256, 0, stream>>>(out1f, W2, h2f);
    k_agg2<<<(NN + 127) / 128, 256, 0, stream>>>(h2f, rowptr, colv, dinv, b2, out);
}

// Round 4
// 285.472 us; speedup vs baseline: 1.6804x; 1.1085x over previous
//
#include <hip/hip_runtime.h>
#include <hip/hip_fp16.h>

#define NN 100000
#define NE 1600000
#define ETOT (NE + NN)          // 1,700,000 CSR entries
#define FIN 128
#define FHID 128
#define FOUT 16

#define SCAN_BLK 512
#define SCAN_NB ((NN + SCAN_BLK - 1) / SCAN_BLK)   // 196

#define NRANGE 8
#define RANGE_W (NN / NRANGE)   // 12500
#define FILL_CHUNKS 256         // blocks per range; grid = 8*256 = 2048

typedef _Float16 f16x8 __attribute__((ext_vector_type(8)));
typedef float f32x4 __attribute__((ext_vector_type(4)));
typedef int int4v __attribute__((ext_vector_type(4)));

// ---------------- graph build ----------------

__global__ void k_init_deg(int* deg) {
    int i = blockIdx.x * blockDim.x + threadIdx.x;
    if (i < NN) deg[i] = 1;                       // self loop
}

__global__ void k_hist(const int* __restrict__ dst, int* deg) {
    int e = blockIdx.x * blockDim.x + threadIdx.x;
    if (e < NE) atomicAdd(&deg[dst[e]], 1);
}

__global__ void k_dinv(const int* __restrict__ deg, float* __restrict__ dinv) {
    int i = blockIdx.x * blockDim.x + threadIdx.x;
    if (i < NN) dinv[i] = rsqrtf((float)deg[i]);  // deg >= 1 always
}

__global__ void k_scan_sums(const int* __restrict__ deg, int* __restrict__ bsums) {
    __shared__ int s[SCAN_BLK];
    int t = threadIdx.x;
    int i = blockIdx.x * SCAN_BLK + t;
    s[t] = (i < NN) ? deg[i] : 0;
    __syncthreads();
    for (int off = SCAN_BLK / 2; off > 0; off >>= 1) {
        if (t < off) s[t] += s[t + off];
        __syncthreads();
    }
    if (t == 0) bsums[blockIdx.x] = s[0];
}

// parallel exclusive scan of the 196 block sums (single block of 256)
__global__ void k_scan_bsums(int* bsums, int* rowptr_last) {
    __shared__ int s[256];
    int t = threadIdx.x;
    int v = (t < SCAN_NB) ? bsums[t] : 0;
    s[t] = v;
    __syncthreads();
    for (int off = 1; off < 256; off <<= 1) {
        int xv = (t >= off) ? s[t - off] : 0;
        __syncthreads();
        s[t] += xv;
        __syncthreads();
    }
    if (t < SCAN_NB) bsums[t] = s[t] - v;         // exclusive
    if (t == 0) *rowptr_last = s[255];            // total == ETOT
}

__global__ void k_scan_final(const int* __restrict__ deg, const int* __restrict__ bsums,
                             int* __restrict__ rowptr, int* __restrict__ cursor) {
    __shared__ int s[SCAN_BLK];
    int t = threadIdx.x;
    int i = blockIdx.x * SCAN_BLK + t;
    int v = (i < NN) ? deg[i] : 0;
    s[t] = v;
    __syncthreads();
    for (int off = 1; off < SCAN_BLK; off <<= 1) {
        int xv = (t >= off) ? s[t - off] : 0;
        __syncthreads();
        s[t] += xv;
        __syncthreads();
    }
    if (i < NN) {
        int excl = bsums[blockIdx.x] + s[t] - v;  // exclusive scan
        rowptr[i] = excl;
        cursor[i] = excl;
    }
}

// CSR fill, dst-range partitioned (range = blockIdx.x % 8 ~ XCD id) so each
// col cache line is written by one XCD. Edge stream loaded NON-TEMPORAL so it
// doesn't evict the ~0.9MB col/cursor write window from the 4MB L2 (R3 showed
// 12x write amplification from streaming evictions).
__global__ __launch_bounds__(256) void k_fill(const int* __restrict__ ei,
                                              int* cursor, int* __restrict__ col) {
    int range = blockIdx.x & (NRANGE - 1);
    int chunk = blockIdx.x >> 3;
    int lo = range * RANGE_W, hi = lo + RANGE_W;
    const int stride = FILL_CHUNKS * 256 * 4;     // 262144
    for (int base = (chunk * 256 + threadIdx.x) * 4; base < NE; base += stride) {
        int4v d4 = __builtin_nontemporal_load((const int4v*)&ei[NE + base]);
        #pragma unroll
        for (int j = 0; j < 4; ++j) {
            int d = d4[j];
            if (d >= lo && d < hi) {
                int s = __builtin_nontemporal_load(&ei[base + j]);
                int pos = atomicAdd(&cursor[d], 1);
                col[pos] = s;
            }
        }
    }
    for (int i = lo + chunk * 256 + threadIdx.x; i < hi; i += FILL_CHUNKS * 256) {
        int pos = atomicAdd(&cursor[i], 1);
        col[pos] = i;
    }
}

// ---------------- W1 transpose+convert: W1T[n][k] fp16 ----------------
// 8 blocks, each a 16-wide k-stripe.

__global__ __launch_bounds__(256) void k_w1t(const float* __restrict__ W,
                                             _Float16* __restrict__ WT) {
    __shared__ _Float16 tl[16][136];
    int b = blockIdx.x;
    int tid = threadIdx.x;
    #pragma unroll
    for (int i = 0; i < 8; ++i) {                 // 16x128 stripe, coalesced read
        int idx = tid + i * 256;
        int k = idx >> 7, n = idx & 127;
        tl[k][n] = (_Float16)W[(b * 16 + k) * FHID + n];
    }
    __syncthreads();
    #pragma unroll
    for (int i = 0; i < 8; ++i) {
        int idx = tid + i * 256;
        int n = idx >> 4, k = idx & 15;
        WT[n * FIN + b * 16 + k] = tl[k][n];
    }
}

// ---------------- GEMM1 (MFMA fp16): h = x @ W1 -> fp16 [NN][128] ----------------
// block 256 = 4 waves; tile 64 rows x 128 cols; mfma_f32_16x16x32_f16.
// A and B frags use the SAME k->(lane-group,reg) mapping, so the result is
// correct for any HW k-permutation; C/D mapping col=lane&15,row=(lane>>4)*4+r
// is m89-verified. LDS XOR-swizzle (k ^= (row&7)*8 halves) avoids the 16-way
// bank conflict of row-major fragment reads.

__global__ __launch_bounds__(256) void k_gemm1(const float* __restrict__ x,
                                               const _Float16* __restrict__ WT,
                                               _Float16* __restrict__ h) {
    __shared__ _Float16 xs[64 * 128];
    __shared__ _Float16 ws[128 * 128];
    int tid = threadIdx.x;
    int m0 = blockIdx.x * 64;
    #pragma unroll
    for (int i = 0; i < 4; ++i) {                 // x tile: 64 rows x 128 k
        int u = tid + i * 256;
        int r = u >> 4;
        int k0 = (u & 15) * 8;
        int row = m0 + r;
        f16x8 v = {};
        if (row < NN) {
            float4 a = *(const float4*)&x[(size_t)row * FIN + k0];
            float4 b = *(const float4*)&x[(size_t)row * FIN + k0 + 4];
            v[0] = (_Float16)a.x; v[1] = (_Float16)a.y;
            v[2] = (_Float16)a.z; v[3] = (_Float16)a.w;
            v[4] = (_Float16)b.x; v[5] = (_Float16)b.y;
            v[6] = (_Float16)b.z; v[7] = (_Float16)b.w;
        }
        *(f16x8*)&xs[r * 128 + (k0 ^ ((r & 7) * 8))] = v;
    }
    #pragma unroll
    for (int i = 0; i < 8; ++i) {                 // W tile: 128 n x 128 k (fp16, L2-hit)
        int u = tid + i * 256;
        int n = u >> 4;
        int k0 = (u & 15) * 8;
        f16x8 v = *(const f16x8*)&WT[n * FIN + k0];
        *(f16x8*)&ws[n * 128 + (k0 ^ ((n & 7) * 8))] = v;
    }
    __syncthreads();
    int wave = tid >> 6, lane = tid & 63;
    int lm = lane & 15, lg = lane >> 4;
    f32x4 acc[8];
    #pragma unroll
    for (int t = 0; t < 8; ++t) acc[t] = (f32x4){0.f, 0.f, 0.f, 0.f};
    int am = wave * 16 + lm;                      // A row within tile
    #pragma unroll
    for (int s = 0; s < 4; ++s) {                 // K steps of 32
        int ka = s * 32 + lg * 8;
        f16x8 af = *(const f16x8*)&xs[am * 128 + (ka ^ ((am & 7) * 8))];
        #pragma unroll
        for (int t = 0; t < 8; ++t) {
            int bn = t * 16 + lm;
            f16x8 bf = *(const f16x8*)&ws[bn * 128 + (ka ^ ((bn & 7) * 8))];
            acc[t] = __builtin_amdgcn_mfma_f32_16x16x32_f16(af, bf, acc[t], 0, 0, 0);
        }
    }
    #pragma unroll
    for (int t = 0; t < 8; ++t) {
        int coln = t * 16 + lm;
        #pragma unroll
        for (int r = 0; r < 4; ++r) {
            int grow = m0 + wave * 16 + lg * 4 + r;
            if (grow < NN) h[(size_t)grow * FHID + coln] = (_Float16)acc[t][r];
        }
    }
}

// ---------------- aggregation helpers ----------------

__device__ __forceinline__ void acc_row8(float* acc, int4 raw, float d) {
    const __half2* p = reinterpret_cast<const __half2*>(&raw);
    #pragma unroll
    for (int j = 0; j < 4; ++j) {
        float2 f = __half22float2(p[j]);
        acc[2 * j]     += f.x * d;
        acc[2 * j + 1] += f.y * d;
    }
}

// ---------------- Agg1 + bias + ReLU -> out1 fp16 [NN][64] half2 ----------------

__global__ __launch_bounds__(256) void k_agg1(const __half2* __restrict__ hf,
                                              const int* __restrict__ rowptr,
                                              const int* __restrict__ col,
                                              const float* __restrict__ dinv,
                                              const float* __restrict__ b1,
                                              __half2* __restrict__ out1) {
    int tid = threadIdx.x;
    int node = blockIdx.x * 16 + (tid >> 4);      // grid 6250 exact
    int lane = tid & 15;                          // features lane*8 .. lane*8+7
    int beg = rowptr[node];
    int end = rowptr[node + 1];
    float acc[8] = {};
    int e = beg;
    for (; e + 4 <= end; e += 4) {
        int s0 = col[e], s1 = col[e + 1], s2 = col[e + 2], s3 = col[e + 3];
        float d0 = dinv[s0], d1 = dinv[s1], d2 = dinv[s2], d3 = dinv[s3];
        int4 r0 = *reinterpret_cast<const int4*>(hf + (size_t)s0 * 64 + lane * 4);
        int4 r1 = *reinterpret_cast<const int4*>(hf + (size_t)s1 * 64 + lane * 4);
        int4 r2 = *reinterpret_cast<const int4*>(hf + (size_t)s2 * 64 + lane * 4);
        int4 r3 = *reinterpret_cast<const int4*>(hf + (size_t)s3 * 64 + lane * 4);
        acc_row8(acc, r0, d0);
        acc_row8(acc, r1, d1);
        acc_row8(acc, r2, d2);
        acc_row8(acc, r3, d3);
    }
    for (; e < end; ++e) {
        int s = col[e];
        float d = dinv[s];
        int4 r = *reinterpret_cast<const int4*>(hf + (size_t)s * 64 + lane * 4);
        acc_row8(acc, r, d);
    }
    float di = dinv[node];
    float4 bA = *(const float4*)&b1[lane * 8];
    float4 bB = *(const float4*)&b1[lane * 8 + 4];
    float o[8];
    o[0] = fmaxf(acc[0] * di + bA.x, 0.f);
    o[1] = fmaxf(acc[1] * di + bA.y, 0.f);
    o[2] = fmaxf(acc[2] * di + bA.z, 0.f);
    o[3] = fmaxf(acc[3] * di + bA.w, 0.f);
    o[4] = fmaxf(acc[4] * di + bB.x, 0.f);
    o[5] = fmaxf(acc[5] * di + bB.y, 0.f);
    o[6] = fmaxf(acc[6] * di + bB.z, 0.f);
    o[7] = fmaxf(acc[7] * di + bB.w, 0.f);
    __half2 ph[4];
    #pragma unroll
    for (int j = 0; j < 4; ++j) ph[j] = __floats2half2_rn(o[2 * j], o[2 * j + 1]);
    *reinterpret_cast<int4*>(out1 + (size_t)node * 64 + lane * 4) =
        *reinterpret_cast<int4*>(ph);
}

// ---------------- GEMM2: h2 = out1 @ W2 -> fp16 [NN][8] half2 ----------------

__global__ __launch_bounds__(256) void k_gemm2(const __half2* __restrict__ a,
                                               const float* __restrict__ W,
                                               __half2* __restrict__ h2) {
    __shared__ __half2 xs[64][68];                // 64 rows x 64 half2 (+4 pad)
    __shared__ float ws[FHID][FOUT];
    int tid = threadIdx.x;
    int m0 = blockIdx.x * 64;
    #pragma unroll
    for (int i = 0; i < 8; ++i) {                 // W2: 128x16
        int idx = tid + i * 256;
        ws[idx >> 4][idx & 15] = W[idx];
    }
    #pragma unroll
    for (int i = 0; i < 4; ++i) {                 // a tile: 64 rows x 16 int4
        int idx = tid + i * 256;
        int r = idx >> 4, q = idx & 15;
        int row = m0 + r;
        int4 v = make_int4(0, 0, 0, 0);
        if (row < NN) v = *reinterpret_cast<const int4*>(a + (size_t)row * 64 + q * 4);
        *reinterpret_cast<int4*>(&xs[r][q * 4]) = v;
    }
    __syncthreads();
    int cp = tid & 7, r = tid >> 3;               // r in 0..31
    float a00 = 0.f, a01 = 0.f, a10 = 0.f, a11 = 0.f;
    #pragma unroll 8
    for (int k2 = 0; k2 < 64; ++k2) {
        float2 f0 = __half22float2(xs[r][k2]);
        float2 f1 = __half22float2(xs[r + 32][k2]);
        float wa0 = ws[2 * k2][2 * cp],     wb0 = ws[2 * k2][2 * cp + 1];
        float wa1 = ws[2 * k2 + 1][2 * cp], wb1 = ws[2 * k2 + 1][2 * cp + 1];
        a00 += f0.x * wa0 + f0.y * wa1;
        a01 += f0.x * wb0 + f0.y * wb1;
        a10 += f1.x * wa0 + f1.y * wa1;
        a11 += f1.x * wb0 + f1.y * wb1;
    }
    int row0 = m0 + r, row1 = m0 + r + 32;
    if (row0 < NN) h2[(size_t)row0 * 8 + cp] = __floats2half2_rn(a00, a01);
    if (row1 < NN) h2[(size_t)row1 * 8 + cp] = __floats2half2_rn(a10, a11);
}

// ---------------- Agg2 + bias -> out fp32 ----------------

__global__ __launch_bounds__(256) void k_agg2(const __half2* __restrict__ h2,
                                              const int* __restrict__ rowptr,
                                              const int* __restrict__ col,
                                              const float* __restrict__ dinv,
                                              const float* __restrict__ b2,
                                              float* __restrict__ out) {
    int tid = threadIdx.x;
    int node = blockIdx.x * 128 + (tid >> 1);
    if (node >= NN) return;
    int l = tid & 1;                              // features l*8 .. l*8+7
    int beg = rowptr[node];
    int end = rowptr[node + 1];
    float acc[8] = {};
    int e = beg;
    for (; e + 4 <= end; e += 4) {
        int s0 = col[e], s1 = col[e + 1], s2 = col[e + 2], s3 = col[e + 3];
        float d0 = dinv[s0], d1 = dinv[s1], d2 = dinv[s2], d3 = dinv[s3];
        int4 r0 = *reinterpret_cast<const int4*>(h2 + (size_t)s0 * 8 + l * 4);
        int4 r1 = *reinterpret_cast<const int4*>(h2 + (size_t)s1 * 8 + l * 4);
        int4 r2 = *reinterpret_cast<const int4*>(h2 + (size_t)s2 * 8 + l * 4);
        int4 r3 = *reinterpret_cast<const int4*>(h2 + (size_t)s3 * 8 + l * 4);
        acc_row8(acc, r0, d0);
        acc_row8(acc, r1, d1);
        acc_row8(acc, r2, d2);
        acc_row8(acc, r3, d3);
    }
    for (; e < end; ++e) {
        int s = col[e];
        float d = dinv[s];
        int4 r = *reinterpret_cast<const int4*>(h2 + (size_t)s * 8 + l * 4);
        acc_row8(acc, r, d);
    }
    float di = dinv[node];
    float4 bA = *(const float4*)&b2[l * 8];
    float4 bB = *(const float4*)&b2[l * 8 + 4];
    float4 oA, oB;
    oA.x = acc[0] * di + bA.x;  oA.y = acc[1] * di + bA.y;
    oA.z = acc[2] * di + bA.z;  oA.w = acc[3] * di + bA.w;
    oB.x = acc[4] * di + bB.x;  oB.y = acc[5] * di + bB.y;
    oB.z = acc[6] * di + bB.z;  oB.w = acc[7] * di + bB.w;
    *(float4*)&out[(size_t)node * 16 + l * 8] = oA;
    *(float4*)&out[(size_t)node * 16 + l * 8 + 4] = oB;
}

// ---------------- launch ----------------

extern "C" void kernel_launch(void* const* d_in, const int* in_sizes, int n_in,
                              void* d_out, int out_size, void* d_ws, size_t ws_size,
                              hipStream_t stream) {
    const float* x  = (const float*)d_in[0];
    const int*   ei = (const int*)d_in[1];       // [2][NE]: row0=src, row1=dst
    const float* W1 = (const float*)d_in[2];
    const float* b1 = (const float*)d_in[3];
    const float* W2 = (const float*)d_in[4];
    const float* b2 = (const float*)d_in[5];
    float* out = (float*)d_out;

    char* ws = (char*)d_ws;
    size_t off = 0;
    #define WS_ALLOC(ptr_t, name, bytes) \
        ptr_t name = (ptr_t)(ws + off); off = (off + (size_t)(bytes) + 511) & ~(size_t)511;
    WS_ALLOC(int*,       degI,   (size_t)NN * 4)
    WS_ALLOC(int*,       rowptr, ((size_t)NN + 1) * 4)
    WS_ALLOC(int*,       cursor, (size_t)NN * 4)
    WS_ALLOC(int*,       colv,   (size_t)ETOT * 4)
    WS_ALLOC(float*,     dinv,   (size_t)NN * 4)
    WS_ALLOC(int*,       bsums,  (size_t)SCAN_NB * 4)
    WS_ALLOC(_Float16*,  w1t,    (size_t)FIN * FHID * 2)
    WS_ALLOC(_Float16*,  hf,     (size_t)NN * FHID * 2)
    WS_ALLOC(__half2*,   out1f,  (size_t)NN * FHID * 2)
    WS_ALLOC(__half2*,   h2f,    (size_t)NN * FOUT * 2)
    #undef WS_ALLOC
    (void)ws_size; (void)in_sizes; (void)n_in; (void)out_size;

    // graph build
    k_init_deg<<<(NN + 255) / 256, 256, 0, stream>>>(degI);
    k_hist<<<(NE + 255) / 256, 256, 0, stream>>>(ei + NE, degI);
    k_dinv<<<(NN + 255) / 256, 256, 0, stream>>>(degI, dinv);
    k_scan_sums<<<SCAN_NB, SCAN_BLK, 0, stream>>>(degI, bsums);
    k_scan_bsums<<<1, 256, 0, stream>>>(bsums, rowptr + NN);
    k_scan_final<<<SCAN_NB, SCAN_BLK, 0, stream>>>(degI, bsums, rowptr, cursor);
    k_fill<<<NRANGE * FILL_CHUNKS, 256, 0, stream>>>(ei, cursor, colv);

    // layer 1
    k_w1t<<<8, 256, 0, stream>>>(W1, w1t);
    k_gemm1<<<(NN + 63) / 64, 256, 0, stream>>>(x, w1t, hf);
    k_agg1<<<NN / 16, 256, 0, stream>>>((const __half2*)hf, rowptr, colv, dinv, b1, out1f);

    // layer 2
    k_gemm2<<<(NN + 63) / 64, 256, 0, stream>>>(out1f, W2, h2f);
    k_agg2<<<(NN + 127) / 128, 256, 0, stream>>>(h2f, rowptr, colv, dinv, b2, out);
}